// Round 1
// baseline (79.089 us; speedup 1.0000x reference)
//
#include <hip/hip_runtime.h>
#include <math.h>

// ColBERT pairwise late-interaction score — R10: split Lk across 2 blocks/o.
//
// R7/R9 (75.3/75.7 us total, kernel ~11.3 us) used grid=128 (one block per o)
// -> only 128 of 256 CUs active. Per-CU sustainable HBM BW ~24 GB/s means the
// 131 KB/block k-staging phase alone was >=5.5 us. This version:
//   kernel A (grid 256): block (o, h) stages k rows [h*128, h*128+128),
//     computes partial sum_j exp(alpha*S) over its half for each live (b,i),
//     writes f32 partials to ws[2][B][O][LQ] (2 MB of harness workspace).
//   kernel B (grid 256): sums halves, log, reduce over i, masks, scale,
//     writes ALL out[b,o] (dead-b rows re-derived from q_mask directly, so
//     no ws memset needed; live slots are always freshly written by A).
//
// Numerics unchanged: S <= 1 -> alpha*S <= 12, exp never overflows; masked j
// adds -1e30 before exp -> exact 0; valid j >= e^-12 so (s_h0+s_h1) == 0 iff
// the row is fully k-masked across BOTH halves (-inf -> zero). The exp-sum
// splits exactly across j-halves (no running-max needed: bounded exponent).

#define ALPHA 12.0f

constexpr int B_  = 64;
constexpr int LQ  = 32;
constexpr int O_  = 128;
constexpr int LK  = 256;
constexpr int LKH = 128;           // j-rows per block (Lk / 2)
constexpr int D_  = 128;
constexpr int LDH = D_ + 8;        // f16 row stride 136 (272 B), 16B-aligned

typedef _Float16 half8   __attribute__((ext_vector_type(8)));
typedef _Float16 half4_t __attribute__((ext_vector_type(4)));
typedef float    f32x4   __attribute__((ext_vector_type(4)));

__global__ __launch_bounds__(256, 1)
void colbert_partial_kernel(const float* __restrict__ q,       // [B, Lq, D]
                            const float* __restrict__ k,       // [O, Lk, D]
                            const int*  __restrict__ q_mask,   // [B, Lq] 0/1
                            const int*  __restrict__ k_mask,   // [O, Lk] 0/1
                            float* __restrict__ ws)            // [2][B][O][LQ]
{
    __shared__ _Float16 kl[LKH][LDH];       // 34816 B
    __shared__ _Float16 ql2[2][LQ][LDH];    // 17408 B (pair of q tiles)
    __shared__ float rk[LKH];               // 1/||k_j||
    __shared__ float bjs[LKH];              // 0 or -1e30
    __shared__ float rqa2[2][LQ];           // ALPHA/||q_i||
    __shared__ float part2[2][2][LQ];       // [pair][col-half][row]
    __shared__ int   lbm[B_ + 1];           // [0]=M, [1+m]=live b

    const int o     = blockIdx.x >> 1;
    const int h     = blockIdx.x & 1;
    const int t     = threadIdx.x;
    const int lane  = t & 63;
    const int w     = t >> 6;
    const int row16 = lane & 15;
    const int quad  = lane >> 4;

    // ---- wave 0 ONLY: q_mask scan + ballot; waves 1-3 go straight to k ----
    if (w == 0) {
        const int4* qm4 = (const int4*)q_mask;     // [64][32] ints, lane = b
        int4 mm[8];
        #pragma unroll
        for (int u = 0; u < 8; ++u)
            mm[u] = qm4[lane * 8 + u];
        int any = 0;
        #pragma unroll
        for (int u = 0; u < 8; ++u)
            any |= mm[u].x | mm[u].y | mm[u].z | mm[u].w;
        const bool live = (any == 0);
        unsigned long long mb = __ballot(live);
        if (live) {
            int rank = __popcll(mb & ((1ull << lane) - 1ull));
            lbm[1 + rank] = lane;
        }
        if (lane == 0) lbm[0] = (int)__popcll(mb);
    }

    // ---- all waves: half k tile load (64 KB), coalesced float4 ----
    const float4* kg = (const float4*)(k + ((size_t)o * LK + (size_t)h * LKH) * D_);
    float4 kv[16];
    #pragma unroll
    for (int r = 0; r < 16; ++r)
        kv[r] = kg[t + 256 * r];                   // 128 rows x 32 float4
    const int km = (t < LKH) ? k_mask[o * LK + h * LKH + t] : 0;

    #pragma unroll
    for (int r = 0; r < 16; ++r) {
        int idx = t + 256 * r;
        int j = idx >> 5, c4 = idx & 31;
        half4_t hh;
        hh[0] = (_Float16)kv[r].x; hh[1] = (_Float16)kv[r].y;
        hh[2] = (_Float16)kv[r].z; hh[3] = (_Float16)kv[r].w;
        *(half4_t*)&kl[j][c4 * 4] = hh;
    }
    __syncthreads();                               // kl + lbm visible

    const int M = lbm[0];
    if (M == 0) return;                            // block-uniform

    // ---- live b's in pairs; iteration 0 overlaps q loads with k norms ----
    int midx = 0;
    bool first = true;
    while (midx < M) {
        const int  b0     = lbm[1 + midx];
        const bool has_b1 = (midx + 1 < M);
        const int  b1     = lbm[1 + (has_b1 ? midx + 1 : midx)];
        midx += 2;

        // issue q[b0], q[b1] global loads FIRST (latency hides under norms)
        const float4* qg0 = (const float4*)(q + (size_t)b0 * LQ * D_);
        const float4* qg1 = (const float4*)(q + (size_t)b1 * LQ * D_);
        float4 qv0[4], qv1[4];
        #pragma unroll
        for (int r = 0; r < 4; ++r) {
            qv0[r] = qg0[t + 256 * r];
            qv1[r] = qg1[t + 256 * r];
        }

        // k norms + mask bias on iteration 0 (DS/VALU while q in flight)
        if (first) {
            if (t < LKH) {
                float ss = 0.f;
                #pragma unroll
                for (int p = 0; p < 16; ++p) {
                    half8 hh = *(const half8*)&kl[t][p * 8];
                    #pragma unroll
                    for (int e = 0; e < 8; ++e) {
                        float x = (float)hh[e];
                        ss = fmaf(x, x, ss);
                    }
                }
                rk[t]  = 1.0f / fmaxf(sqrtf(ss), 1e-12f);
                bjs[t] = (km != 0) ? -1e30f : 0.0f;
            }
            first = false;
        }

        // convert + stage q pair
        #pragma unroll
        for (int r = 0; r < 4; ++r) {
            int idx = t + 256 * r;                 // [32][32] float4
            int i = idx >> 5, c4 = idx & 31;
            half4_t h0, h1;
            h0[0] = (_Float16)qv0[r].x; h0[1] = (_Float16)qv0[r].y;
            h0[2] = (_Float16)qv0[r].z; h0[3] = (_Float16)qv0[r].w;
            h1[0] = (_Float16)qv1[r].x; h1[1] = (_Float16)qv1[r].y;
            h1[2] = (_Float16)qv1[r].z; h1[3] = (_Float16)qv1[r].w;
            *(half4_t*)&ql2[0][i][c4 * 4] = h0;
            *(half4_t*)&ql2[1][i][c4 * 4] = h1;
        }
        __syncthreads();                           // ql2 + rk/bjs visible

        // q norms: t<64 covers both pair members (pb = t>>5, i = t&31)
        if (t < 64) {
            const int pb = t >> 5, i = t & 31;
            float ss = 0.f;
            #pragma unroll
            for (int p = 0; p < 16; ++p) {
                half8 hh = *(const half8*)&ql2[pb][i][p * 8];
                #pragma unroll
                for (int e = 0; e < 8; ++e) {
                    float x = (float)hh[e];
                    ss = fmaf(x, x, ss);
                }
            }
            rqa2[pb][i] = ALPHA / fmaxf(sqrtf(ss), 1e-12f);
        }
        __syncthreads();

        // MFMA: wave w -> rows [16*(w>>1), +16), cols [(w&1)*64, +64)
        const int i0 = (w >> 1) * 16;
        const int j0 = (w & 1) * 64;

        half8 afrag[2][4];
        #pragma unroll
        for (int pb = 0; pb < 2; ++pb)
            #pragma unroll
            for (int kk = 0; kk < 4; ++kk)
                afrag[pb][kk] =
                    *(const half8*)&ql2[pb][i0 + row16][kk * 32 + quad * 8];

        float rqv[2][4];
        #pragma unroll
        for (int pb = 0; pb < 2; ++pb)
            #pragma unroll
            for (int rg = 0; rg < 4; ++rg)
                rqv[pb][rg] = rqa2[pb][i0 + quad * 4 + rg];

        float esum[2][4] = {{0.f,0.f,0.f,0.f},{0.f,0.f,0.f,0.f}};
        #pragma unroll
        for (int c = 0; c < 4; ++c) {
            const int jt = j0 + c * 16;
            f32x4 acc0 = {0.f, 0.f, 0.f, 0.f};
            f32x4 acc1 = {0.f, 0.f, 0.f, 0.f};
            #pragma unroll
            for (int kk = 0; kk < 4; ++kk) {
                half8 bfrag =
                    *(const half8*)&kl[jt + row16][kk * 32 + quad * 8];
                acc0 = __builtin_amdgcn_mfma_f32_16x16x32_f16(
                           afrag[0][kk], bfrag, acc0, 0, 0, 0);
                acc1 = __builtin_amdgcn_mfma_f32_16x16x32_f16(
                           afrag[1][kk], bfrag, acc1, 0, 0, 0);
            }
            // C layout: col = lane&15 (j), row = quad*4+reg (i)
            const float rkj = rk[jt + row16];
            const float bb  = bjs[jt + row16];
            #pragma unroll
            for (int rg = 0; rg < 4; ++rg) {
                esum[0][rg] += __expf(acc0[rg] * rqv[0][rg] * rkj + bb);
                esum[1][rg] += __expf(acc1[rg] * rqv[1][rg] * rkj + bb);
            }
        }
        #pragma unroll
        for (int pb = 0; pb < 2; ++pb) {
            #pragma unroll
            for (int rg = 0; rg < 4; ++rg) {
                float e = esum[pb][rg];
                e += __shfl_xor(e, 1);
                e += __shfl_xor(e, 2);
                e += __shfl_xor(e, 4);
                e += __shfl_xor(e, 8);
                esum[pb][rg] = e;
            }
            if (row16 == 0)
                #pragma unroll
                for (int rg = 0; rg < 4; ++rg)
                    part2[pb][w & 1][i0 + quad * 4 + rg] = esum[pb][rg];
        }
        __syncthreads();

        // write partial esum for this j-half: ws[h][b][o][i] (coalesced 128B)
        if (t < 64) {
            const int pb = t >> 5, i = t & 31;
            if (pb == 0 || has_b1) {
                const int b = pb ? b1 : b0;
                const float s = part2[pb][0][i] + part2[pb][1][i];
                ws[(((size_t)h * B_ + b) * O_ + o) * LQ + i] = s;
            }
        }
        // next-iter ql2/part2 writes are gated by the two barriers ahead —
        // same protection structure as R6/R7.
    }
}

__global__ __launch_bounds__(256, 1)
void colbert_finalize_kernel(const float* __restrict__ ws,      // [2][B][O][LQ]
                             const int*  __restrict__ q_mask,   // [B, Lq]
                             const float* __restrict__ logit_scale,
                             float* __restrict__ out)           // [B, O]
{
    const int t    = threadIdx.x;
    const int lane = t & 63;
    const int w    = t >> 6;
    const int pb   = lane >> 5;                    // which (b,o) pair of 2
    const int i    = lane & 31;                    // q row

    const float ls     = logit_scale[0];
    const float scale  = fminf(__expf(ls), 100.0f);
    const float inv_ln = 1.0f / (sqrtf((float)(LQ * LK)) + 1e-6f);
    const int   gw     = blockIdx.x * 4 + w;       // global wave id [0,1024)

    #pragma unroll
    for (int it = 0; it < 4; ++it) {
        const int p = it * 2048 + gw * 2 + pb;     // (b,o) index [0,8192)
        const int b = p >> 7;
        const int o = p & 127;

        const float s0 = ws[(((size_t)0 * B_ + b) * O_ + o) * LQ + i];
        const float s1 = ws[(((size_t)1 * B_ + b) * O_ + o) * LQ + i];
        const int   qm = q_mask[b * LQ + i];

        const float s = s0 + s1;
        const bool  badrow = (s <= 0.f);           // row fully k-masked
        float tot = __logf(fmaxf(s, 1e-38f));
        tot += __shfl_xor(tot, 16);
        tot += __shfl_xor(tot, 8);
        tot += __shfl_xor(tot, 4);
        tot += __shfl_xor(tot, 2);
        tot += __shfl_xor(tot, 1);

        unsigned long long zb = __ballot(badrow);
        unsigned long long qb = __ballot(qm != 0); // any q pad -> row b dead
        if (i == 0) {
            unsigned long long half_mask =
                pb ? 0xFFFFFFFF00000000ull : 0x00000000FFFFFFFFull;
            float res = 0.f;
            if (((zb | qb) & half_mask) == 0ull)
                res = (tot * (1.0f / ALPHA)) * inv_ln * scale;
            out[b * O_ + o] = res;
        }
    }
}

extern "C" void kernel_launch(void* const* d_in, const int* in_sizes, int n_in,
                              void* d_out, int out_size, void* d_ws, size_t ws_size,
                              hipStream_t stream) {
    const float* q           = (const float*)d_in[0];
    const float* k           = (const float*)d_in[1];
    const int*   q_mask      = (const int*)d_in[2];
    const int*   k_mask      = (const int*)d_in[3];
    const float* logit_scale = (const float*)d_in[4];
    float* out = (float*)d_out;
    float* ws  = (float*)d_ws;                     // needs 2*64*128*32*4 = 2 MB

    colbert_partial_kernel<<<O_ * 2, 256, 0, stream>>>(q, k, q_mask, k_mask, ws);
    colbert_finalize_kernel<<<256, 256, 0, stream>>>(ws, q_mask, logit_scale, out);
}